// Round 1
// baseline (92.142 us; speedup 1.0000x reference)
//
#include <hip/hip_runtime.h>
#include <math.h>

#define NB_TOTAL 65536
#define NOBS 256
#define OUTS 773            // 2 + 514 + 257
#define ROWS_PER_BLOCK 64
#define THREADS 256

// Output row layout (f32):
//  [0..1]    x31
//  [2+2j]    G_s[j][0], [3+2j] G_s[j][1]   j in 0..255   -> 2..513
//  [514,515] G_o
//  [516+j]   h_s[j]                                      -> 516..771
//  [772]     h_o

__global__ __launch_bounds__(THREADS, 4) void barriernet_kernel(
    const float* __restrict__ x,
    const float* __restrict__ obstacles,
    const float* __restrict__ input_mean,
    const float* __restrict__ input_std,
    const float* __restrict__ W1,  const float* __restrict__ b1,
    const float* __restrict__ W21, const float* __restrict__ b21,
    const float* __restrict__ W22, const float* __restrict__ b22,
    const float* __restrict__ W31, const float* __restrict__ b31,
    const float* __restrict__ W32, const float* __restrict__ b32,
    float* __restrict__ out)
{
    __shared__ float params[ROWS_PER_BLOCK][16];

    const int tid = threadIdx.x;
    const int blockBase = blockIdx.x * ROWS_PER_BLOCK;

    // ---------------- Phase A: per-row MLP + dynamics (threads 0..63) -------
    if (tid < ROWS_PER_BLOCK) {
        const int row = blockBase + tid;

        float xr[8];
        {
            const float4 xa = *(const float4*)(x + (size_t)row * 8);
            const float4 xb = *(const float4*)(x + (size_t)row * 8 + 4);
            xr[0]=xa.x; xr[1]=xa.y; xr[2]=xa.z; xr[3]=xa.w;
            xr[4]=xb.x; xr[5]=xb.y; xr[6]=xb.z; xr[7]=xb.w;
        }

        // ---- pass 1: hid -> x21 -> x31 ----
        float acc[32];
        #pragma unroll
        for (int k = 0; k < 32; ++k) acc[k] = b21[k];

        #pragma unroll 1
        for (int i0 = 0; i0 < 128; i0 += 8) {
            float hh[8];
            #pragma unroll
            for (int u = 0; u < 8; ++u) {
                float a = b1[i0 + u];
                #pragma unroll
                for (int k = 0; k < 8; ++k)
                    a = fmaf(xr[k], W1[k * 128 + i0 + u], a);
                hh[u] = fmaxf(a, 0.0f);
            }
            #pragma unroll
            for (int u = 0; u < 8; ++u) {
                #pragma unroll
                for (int k = 0; k < 32; ++k)
                    acc[k] = fmaf(hh[u], W21[(i0 + u) * 32 + k], acc[k]);
            }
        }
        float x31_0 = b31[0], x31_1 = b31[1];
        #pragma unroll
        for (int k = 0; k < 32; ++k) {
            float a21 = fmaxf(acc[k], 0.0f);
            x31_0 = fmaf(a21, W31[k * 2 + 0], x31_0);
            x31_1 = fmaf(a21, W31[k * 2 + 1], x31_1);
        }

        // ---- pass 2: hid -> x22 -> x32 (recompute hid, saves 32 VGPRs) ----
        #pragma unroll
        for (int k = 0; k < 32; ++k) acc[k] = b22[k];

        #pragma unroll 1
        for (int i0 = 0; i0 < 128; i0 += 8) {
            float hh[8];
            #pragma unroll
            for (int u = 0; u < 8; ++u) {
                float a = b1[i0 + u];
                #pragma unroll
                for (int k = 0; k < 8; ++k)
                    a = fmaf(xr[k], W1[k * 128 + i0 + u], a);
                hh[u] = fmaxf(a, 0.0f);
            }
            #pragma unroll
            for (int u = 0; u < 8; ++u) {
                #pragma unroll
                for (int k = 0; k < 32; ++k)
                    acc[k] = fmaf(hh[u], W22[(i0 + u) * 32 + k], acc[k]);
            }
        }
        float z0 = b32[0], z1 = b32[1];
        #pragma unroll
        for (int k = 0; k < 32; ++k) {
            float a22 = fmaxf(acc[k], 0.0f);
            z0 = fmaf(a22, W32[k * 2 + 0], z0);
            z1 = fmaf(a22, W32[k * 2 + 1], z1);
        }
        const float p0 = 4.0f / (1.0f + __expf(-z0));
        const float p1 = 4.0f / (1.0f + __expf(-z1));

        // ---- dynamics ----
        float x0v[8];
        #pragma unroll
        for (int k = 0; k < 8; ++k)
            x0v[k] = fmaf(xr[k], input_std[k], input_mean[k]);
        const float px = x0v[0], py = x0v[1], th = x0v[2], v = x0v[3];
        const float opx = x0v[4], opy = x0v[5], oth = x0v[6], ov = x0v[7];

        float st, ct, sto, cto;
        sincosf(th,  &st,  &ct);
        sincosf(oth, &sto, &cto);

        const float ps  = p0 + p1;
        const float pp  = p0 * p1;
        const float tvs = 2.0f * v * st;
        const float tvc = 2.0f * v * ct;
        const float tc  = 2.0f * ct;
        const float ts  = 2.0f * st;
        const float hc  = 2.0f * v * v;     // Lf2b (self)

        // opponent barrier (Ro = 2*0.5 + 0.1 = 1.1, Ro^2 = 1.21)
        const float dxo = px - opx, dyo = py - opy;
        const float ob  = dxo * dxo + dyo * dyo - 1.21f;
        const float rvx = v * ct - ov * cto;
        const float rvy = v * st - ov * sto;
        const float obd = 2.0f * (dxo * rvx + dyo * rvy);
        const float cth_sum = ct * cto - st * sto;     // cos(th + oth)
        const float oLf2b = 2.0f * (v * v + ov * ov - 2.0f * v * ov * cth_sum);
        const float Go0 = dxo * tvs - dyo * tvc;
        const float Go1 = -(dxo * tc + dyo * ts);
        const float ho  = oLf2b + ps * obd + pp * ob;

        float* rb = out + (size_t)row * OUTS;
        rb[0]   = x31_0;
        rb[1]   = x31_1;
        rb[514] = Go0;
        rb[515] = Go1;
        rb[772] = ho;

        params[tid][0] = px;  params[tid][1] = py;
        params[tid][2] = tvs; params[tid][3] = tvc;
        params[tid][4] = tc;  params[tid][5] = ts;
        params[tid][6] = ps;  params[tid][7] = pp;
        params[tid][8] = hc;
    }
    __syncthreads();

    // ---------------- Phase B: per-(row, obstacle) barriers -----------------
    const int lane = tid & 63;
    const int wave = tid >> 6;

    // each lane owns obstacles {lane, lane+64, lane+128, lane+192}
    float ox[4], oy[4], r2[4];
    #pragma unroll
    for (int c = 0; c < 4; ++c) {
        const float* o = obstacles + (size_t)(c * 64 + lane) * 3;
        const float a = o[0], b = o[1], r = o[2] + 0.6f;  // R = 0.5 + rad + 0.1
        ox[c] = a; oy[c] = b; r2[c] = r * r;
    }

    #pragma unroll 1
    for (int rr = 0; rr < 16; ++rr) {
        const int rl = wave * 16 + rr;          // uniform per wave -> broadcast reads
        const float4 pA = *(const float4*)&params[rl][0];
        const float4 pB = *(const float4*)&params[rl][4];
        const float  hc = params[rl][8];
        const float px = pA.x, py = pA.y, tvs = pA.z, tvc = pA.w;
        const float tc = pB.x, ts = pB.y, ps  = pB.z, pp  = pB.w;

        float* rb = out + (size_t)(blockBase + rl) * OUTS;

        #pragma unroll
        for (int c = 0; c < 4; ++c) {
            const int j = c * 64 + lane;
            const float dx = px - ox[c];
            const float dy = py - oy[c];
            const float G0   = dx * tvs - dy * tvc;
            const float G1   = -(dx * tc + dy * ts);
            const float bdot = dx * tvc + dy * tvs;
            const float bar  = fmaf(dx, dx, dy * dy) - r2[c];
            const float hv   = fmaf(ps, bdot, fmaf(pp, bar, hc));
            rb[2 + 2 * j] = G0;
            rb[3 + 2 * j] = G1;
            rb[516 + j]   = hv;
        }
    }
}

extern "C" void kernel_launch(void* const* d_in, const int* in_sizes, int n_in,
                              void* d_out, int out_size, void* d_ws, size_t ws_size,
                              hipStream_t stream) {
    const float* x          = (const float*)d_in[0];
    const float* obstacles  = (const float*)d_in[1];
    const float* input_mean = (const float*)d_in[2];
    const float* input_std  = (const float*)d_in[3];
    const float* W1  = (const float*)d_in[4];
    const float* b1  = (const float*)d_in[5];
    const float* W21 = (const float*)d_in[6];
    const float* b21 = (const float*)d_in[7];
    const float* W22 = (const float*)d_in[8];
    const float* b22 = (const float*)d_in[9];
    const float* W31 = (const float*)d_in[10];
    const float* b31 = (const float*)d_in[11];
    const float* W32 = (const float*)d_in[12];
    const float* b32 = (const float*)d_in[13];
    // d_in[14] = sgn (unused by the reference)

    float* out = (float*)d_out;

    const int grid = NB_TOTAL / ROWS_PER_BLOCK;   // 1024
    barriernet_kernel<<<dim3(grid), dim3(THREADS), 0, stream>>>(
        x, obstacles, input_mean, input_std,
        W1, b1, W21, b21, W22, b22, W31, b31, W32, b32, out);
}